// Round 1
// baseline (288.080 us; speedup 1.0000x reference)
//
#include <hip/hip_runtime.h>
#include <hip/hip_bf16.h>
#include <stdint.h>

#define D_ 128
#define NB 64   // index rows per GEMM block

typedef float f32x4 __attribute__((ext_vector_type(4)));
typedef short bf16x8 __attribute__((ext_vector_type(8)));

__device__ inline unsigned short f2bf(float f){
  unsigned x = __float_as_uint(f);
  return (unsigned short)((x + 0x7FFFu + ((x >> 16) & 1u)) >> 16);  // RNE
}
__device__ inline unsigned packbf(float a, float b){
  return (unsigned)f2bf(a) | ((unsigned)f2bf(b) << 16);
}
// monotonic float->u32 key for atomicMax
__device__ inline unsigned fkey(float v){
  unsigned b = __float_as_uint(v);
  return (b & 0x80000000u) ? ~b : (b | 0x80000000u);
}

// ---- normalize queries f32 -> bf16 (one wave per row) ----
__global__ void k_norm_x(const float* __restrict__ x, unsigned short* __restrict__ xn){
  int row = blockIdx.x, lane = threadIdx.x;
  float2 v = reinterpret_cast<const float2*>(x + (size_t)row * D_)[lane];
  float ss = v.x * v.x + v.y * v.y;
  #pragma unroll
  for (int m = 1; m < 64; m <<= 1) ss += __shfl_xor(ss, m);
  float s = 1.0f / fmaxf(sqrtf(ss), 1e-12f);
  reinterpret_cast<unsigned*>(xn + (size_t)row * D_)[lane] = packbf(v.x * s, v.y * s);
}

// ---- class histogram ----
__global__ void k_hist(const int* __restrict__ lab, unsigned* __restrict__ hist, int N, int C){
  __shared__ unsigned lh[1024];
  int t = threadIdx.x;
  for (int c = t; c < 1024; c += 256) lh[c] = 0;
  __syncthreads();
  for (int i = blockIdx.x * 256 + t; i < N; i += gridDim.x * 256)
    atomicAdd(&lh[lab[i]], 1u);
  __syncthreads();
  for (int c = t; c < C; c += 256) { unsigned v = lh[c]; if (v) atomicAdd(&hist[c], v); }
}

// ---- exclusive scan -> per-class cursors (C <= 1024) ----
__global__ void k_scan(const unsigned* __restrict__ hist, unsigned* __restrict__ cursor, int C){
  __shared__ unsigned s[1024];
  int t = threadIdx.x;
  unsigned v = (t < C) ? hist[t] : 0u;
  s[t] = v; __syncthreads();
  for (int off = 1; off < 1024; off <<= 1){
    unsigned u = (t >= off) ? s[t - off] : 0u;
    __syncthreads();
    s[t] += u;
    __syncthreads();
  }
  if (t < C) cursor[t] = s[t] - v;
}

// ---- scatter: build class-sorted permutation ----
__global__ void k_scatter(const int* __restrict__ lab, unsigned* __restrict__ cursor,
                          int* __restrict__ perm, int* __restrict__ slab, int N){
  for (int i = blockIdx.x * 256 + threadIdx.x; i < N; i += gridDim.x * 256){
    int c = lab[i];
    unsigned pos = atomicAdd(&cursor[c], 1u);
    perm[pos] = i;
    slab[pos] = c;
  }
}

// ---- init output with key(-inf) ----
__global__ void k_init_out(unsigned* __restrict__ o, int n){
  int i = blockIdx.x * 256 + threadIdx.x;
  if (i < n) o[i] = 0x007FFFFFu;   // fkey(-inf)
}

// ---- main fused GEMM + segment-max ----
struct __align__(16) GSm {
  unsigned short A[NB * 136];   // bf16 rows, row stride 136 elems (272 B) to dodge bank conflicts
  float sims[16 * 257];         // one 16-row M-tile of sims, padded
  float scale[NB];
  int rowid[NB];
  int clab[NB];
};

__global__ __launch_bounds__(256, 2) void k_gemm(
    const float* __restrict__ emb, const unsigned short* __restrict__ xn,
    const int* __restrict__ perm, const int* __restrict__ slab,
    unsigned* __restrict__ out_u, int N, int C){
  __shared__ GSm sm;
  const int t = threadIdx.x;
  const int base = blockIdx.x * NB;

  if (t < NB){
    int p = base + t; if (p > N - 1) p = N - 1;   // tail-safe duplicate (same class -> max unchanged)
    sm.rowid[t] = perm[p];
    sm.clab[t]  = slab[p];
  }
  __syncthreads();

  // gather 64 index rows (f32), compute norms, store raw bf16 to LDS
  {
    int r = t >> 2, j = t & 3;
    const float4* src = reinterpret_cast<const float4*>(emb + (long)sm.rowid[r] * D_ + j * 32);
    float4 v[8];
    #pragma unroll
    for (int i = 0; i < 8; i++) v[i] = src[i];
    float ss = 0.f;
    #pragma unroll
    for (int i = 0; i < 8; i++) ss += v[i].x*v[i].x + v[i].y*v[i].y + v[i].z*v[i].z + v[i].w*v[i].w;
    ss += __shfl_xor(ss, 1); ss += __shfl_xor(ss, 2);
    sm.scale[r] = 1.0f / fmaxf(sqrtf(ss), 1e-12f);
    unsigned* dst = reinterpret_cast<unsigned*>(&sm.A[r * 136 + j * 32]);
    #pragma unroll
    for (int i = 0; i < 8; i++){
      dst[i * 2]     = packbf(v[i].x, v[i].y);
      dst[i * 2 + 1] = packbf(v[i].z, v[i].w);
    }
  }

  const int w = t >> 6, lane = t & 63;
  const int lr = lane & 15, lg = lane >> 4;

  // B fragments: queries (L2-resident), held in VGPRs for the whole block
  bf16x8 bf[4][4];
  #pragma unroll
  for (int ni = 0; ni < 4; ni++)
    #pragma unroll
    for (int kk = 0; kk < 4; kk++)
      bf[ni][kk] = *reinterpret_cast<const bf16x8*>(
          xn + (size_t)(w * 64 + ni * 16 + lr) * D_ + kk * 32 + lg * 8);

  f32x4 acc[4][4];
  #pragma unroll
  for (int mi = 0; mi < 4; mi++)
    #pragma unroll
    for (int ni = 0; ni < 4; ni++)
      acc[mi][ni] = (f32x4){0.f, 0.f, 0.f, 0.f};

  __syncthreads();

  // D[row=index_row][col=query]; M=64 rows, N'=256 queries (64/wave), K=128
  #pragma unroll
  for (int mi = 0; mi < 4; mi++)
    #pragma unroll
    for (int kk = 0; kk < 4; kk++){
      bf16x8 af = *reinterpret_cast<const bf16x8*>(&sm.A[(mi * 16 + lr) * 136 + kk * 32 + lg * 8]);
      #pragma unroll
      for (int ni = 0; ni < 4; ni++)
        acc[mi][ni] = __builtin_amdgcn_mfma_f32_16x16x32_bf16(af, bf[ni][kk], acc[mi][ni], 0, 0, 0);
    }

  // epilogue: per 16-row tile -> LDS -> sequential class-segment max per query
  int cur = -1; float rm = 0.f;
  for (int mi = 0; mi < 4; mi++){
    __syncthreads();
    #pragma unroll
    for (int ni = 0; ni < 4; ni++)
      #pragma unroll
      for (int rg = 0; rg < 4; rg++){
        int r16 = lg * 4 + rg;
        sm.sims[r16 * 257 + w * 64 + ni * 16 + lr] = acc[mi][ni][rg] * sm.scale[mi * 16 + r16];
      }
    __syncthreads();
    #pragma unroll
    for (int r16 = 0; r16 < 16; r16++){
      int c = sm.clab[mi * 16 + r16];        // uniform broadcast
      float v = sm.sims[r16 * 257 + t];
      if (c != cur){
        if (cur >= 0) atomicMax(&out_u[(size_t)t * C + cur], fkey(rm));
        cur = c; rm = v;
      } else rm = fmaxf(rm, v);
    }
  }
  atomicMax(&out_u[(size_t)t * C + cur], fkey(rm));
}

// ---- unmap keys -> floats (in place) ----
__global__ void k_finalize(unsigned* __restrict__ o, int n){
  int i = blockIdx.x * 256 + threadIdx.x;
  if (i < n){
    unsigned k = o[i];
    o[i] = (k & 0x80000000u) ? (k & 0x7FFFFFFFu) : ~k;
  }
}

extern "C" void kernel_launch(void* const* d_in, const int* in_sizes, int n_in,
                              void* d_out, int out_size, void* d_ws, size_t ws_size,
                              hipStream_t stream){
  const float* x   = (const float*)d_in[0];
  const float* emb = (const float*)d_in[1];
  const int*   lab = (const int*)d_in[2];
  const int B = in_sizes[0] / D_;        // 256
  const int N = in_sizes[1] / D_;        // 200000
  const int C = out_size / B;            // 1000

  char* ws = (char*)d_ws;
  unsigned short* xn = (unsigned short*)ws;
  size_t off = ((size_t)B * D_ * 2 + 255) & ~(size_t)255;
  unsigned* hist   = (unsigned*)(ws + off); off += 4096;
  unsigned* cursor = (unsigned*)(ws + off); off += 4096;
  int* perm = (int*)(ws + off); off += ((size_t)N * 4 + 255) & ~(size_t)255;
  int* slab = (int*)(ws + off);

  k_norm_x<<<B, 64, 0, stream>>>(x, xn);
  hipMemsetAsync(hist, 0, 8192, stream);               // hist + cursor contiguous
  k_hist<<<208, 256, 0, stream>>>(lab, hist, N, C);
  k_scan<<<1, 1024, 0, stream>>>(hist, cursor, C);
  k_scatter<<<208, 256, 0, stream>>>(lab, cursor, perm, slab, N);
  k_init_out<<<(B * C + 255) / 256, 256, 0, stream>>>((unsigned*)d_out, B * C);
  k_gemm<<<(N + NB - 1) / NB, 256, 0, stream>>>(emb, xn, perm, slab, (unsigned*)d_out, N, C);
  k_finalize<<<(B * C + 255) / 256, 256, 0, stream>>>((unsigned*)d_out, B * C);
}